// Round 12
// baseline (182.271 us; speedup 1.0000x reference)
//
#include <hip/hip_runtime.h>

// B=4, S=4096, D_IN=1024, D_QK=D_V=64
// out = softmax(relu(XWq+bq) @ relu(XWk+bk)^T) @ relu(XWv+bv) * mask

typedef short s16x8 __attribute__((ext_vector_type(8)));   // 8 bf16 (4 VGPRs) MFMA frag
typedef float fx4   __attribute__((ext_vector_type(4)));   // MFMA accum frag
typedef unsigned short u16x4 __attribute__((ext_vector_type(4)));

#define LOG2E 1.4426950408889634f

__device__ __forceinline__ unsigned short f2bf(float x) {   // fp32 -> bf16 RTN
    unsigned int u = __float_as_uint(x);
    u += 0x7FFFu + ((u >> 16) & 1u);
    return (unsigned short)(u >> 16);
}
__device__ __forceinline__ float bf2f(unsigned short b) {
    return __uint_as_float(((unsigned int)b) << 16);
}

// ---------------------------------------------------------------------------
// Kernel 1: split W{q,k,v} [1024][64] fp32 into W^T hi/lo bf16 [3][64][1024].
// (unchanged)
// ---------------------------------------------------------------------------
__global__ __launch_bounds__(256) void prep_w_kernel(
    const float* __restrict__ Wq, const float* __restrict__ Wk, const float* __restrict__ Wv,
    unsigned short* __restrict__ wt_hi, unsigned short* __restrict__ wt_lo)
{
    __shared__ __align__(16) unsigned short sh[64][72];   // [c][k_local]
    __shared__ __align__(16) unsigned short sl[64][72];

    const int y  = blockIdx.x;
    const int kt = blockIdx.y;
    const float* W = (y == 0) ? Wq : (y == 1) ? Wk : Wv;
    const int t  = threadIdx.x;

    const int kl = t >> 2;
    const int c0 = (t & 3) * 16;
    const float* src = W + (size_t)(kt * 64 + kl) * 64 + c0;
    #pragma unroll
    for (int j = 0; j < 4; j++) {
        fx4 v = *(const fx4*)(src + j * 4);
        #pragma unroll
        for (int i = 0; i < 4; i++) {
            float x = v[i];
            unsigned short h = f2bf(x);
            unsigned short l = f2bf(x - bf2f(h));
            sh[c0 + j * 4 + i][kl] = h;
            sl[c0 + j * 4 + i][kl] = l;
        }
    }
    __syncthreads();

    const int c  = t >> 2;
    const int k0 = (t & 3) * 16;
    size_t o = (size_t)(y * 64 + c) * 1024 + kt * 64 + k0;
    *(s16x8*)(wt_hi + o)     = *(const s16x8*)&sh[c][k0];
    *(s16x8*)(wt_hi + o + 8) = *(const s16x8*)&sh[c][k0 + 8];
    *(s16x8*)(wt_lo + o)     = *(const s16x8*)&sl[c][k0];
    *(s16x8*)(wt_lo + o + 8) = *(const s16x8*)&sl[c][k0 + 8];
}

// ---------------------------------------------------------------------------
// Kernel 2 (v11): FUSED q/k/v projection, 2 BLOCKS/CU. v10b's counters
// (conflicts 4.76M->41K with ZERO time change; barriers 31->15 neutral;
// every pipe <30% busy at 1 block/CU) point at the one untried mechanism:
// cross-block wave overlap (m114) -- a single 12-wave block drains its
// whole CU at every barrier. v11: M-tile 32, block 384 (6 waves = 6
// col-groups {q,k,v} x 2, each wave 32x32), grid 512 = 2 blocks/CU.
// Fusion kept (X converted once per row per CU); v10b's proven XOR
// swizzle kept (chunk ^= row&7); v2-proven register relays: X depth 4,
// W depth 1 (halved per-thread W volume -> VGPR ~140 under the 168 cap
// at launch_bounds(384,3)). LDS 56KB/block = 112KB/CU. Per-output
// kc/ks/hh-hl-lh MFMA order identical to v10b => bit-identical results.
// ---------------------------------------------------------------------------
__global__ __launch_bounds__(384, 3) void proj_kernel(
    const float* __restrict__ X,
    const unsigned short* __restrict__ wt_hi, const unsigned short* __restrict__ wt_lo,
    const float* __restrict__ bq, const float* __restrict__ bk, const float* __restrict__ bv,
    unsigned short* __restrict__ q_hi, unsigned short* __restrict__ q_lo,
    unsigned short* __restrict__ k_bf, unsigned short* __restrict__ vt_g)
{
    __shared__ __align__(16) unsigned short a_hi[32][64];    // [row][k] swizzled
    __shared__ __align__(16) unsigned short a_lo[32][64];
    __shared__ __align__(16) unsigned short bsh[192][64];    // [col][k] swizzled
    __shared__ __align__(16) unsigned short bsl[192][64];

    const int tid  = threadIdx.x;
    const int lane = tid & 63;
    const int w    = tid >> 6;      // 0..5
    const int quad = lane >> 4;
    const int l15  = lane & 15;
    const int colg = w;             // 0..5 = {q,k,v} x {col half}
    const int y    = colg >> 1;     // 0=q 1=k 2=v
    const int ch   = colg & 1;      // 32-col half within y

    const int m0 = blockIdx.x * 32;

    fx4 acc[2][2];                  // [sub 16 rows][nt 16 cols]
    #pragma unroll
    for (int i = 0; i < 2; i++)
        #pragma unroll
        for (int j = 0; j < 2; j++) acc[i][j] = (fx4){0.f, 0.f, 0.f, 0.f};

    // X staging: threads 0..255, 8 consecutive floats (one 16B bf16 chunk out)
    const int xrow = tid >> 3;        // 0..31 (tid<256)
    const int xch  = tid & 7;         // logical 8-float chunk
    const float* xb = X + (size_t)(m0 + xrow) * 1024 + xch * 8;
    const int xsw  = ((xch ^ (xrow & 7)) << 3);   // swizzled chunk base (shorts)

    // W staging: all 384 threads, 64 shorts hi + 64 lo per kc
    const int wrow = tid >> 1;        // 0..191
    const int wk   = (tid & 1) * 32;  // logical k-offset (shorts)
    const size_t wb = (size_t)wrow * 1024 + wk;

    // register relays: X depth 4 kc, W depth 1 kc
    fx4   xr[4][2];
    s16x8 wrh[4], wrl[4];
    if (tid < 256) {
        #pragma unroll
        for (int d = 0; d < 4; d++) {
            xr[d][0] = *(const fx4*)(xb + d * 64);
            xr[d][1] = *(const fx4*)(xb + d * 64 + 4);
        }
    }
    #pragma unroll
    for (int j = 0; j < 4; j++) {
        wrh[j] = *(const s16x8*)(wt_hi + wb + j * 8);
        wrl[j] = *(const s16x8*)(wt_lo + wb + j * 8);
    }

    #pragma unroll 4
    for (int kc = 0; kc < 16; kc++) {
        if (kc) __syncthreads();   // prev iter's LDS readers done
        // stage kc: X conversion (256 threads) + W from relay (all threads)
        if (tid < 256) {
            fx4 xa = xr[kc & 3][0], xb2 = xr[kc & 3][1];
            unsigned short h0 = f2bf(xa.x), h1 = f2bf(xa.y), h2 = f2bf(xa.z), h3 = f2bf(xa.w);
            unsigned short h4 = f2bf(xb2.x), h5 = f2bf(xb2.y), h6 = f2bf(xb2.z), h7 = f2bf(xb2.w);
            unsigned short l0 = f2bf(xa.x - bf2f(h0)), l1 = f2bf(xa.y - bf2f(h1));
            unsigned short l2 = f2bf(xa.z - bf2f(h2)), l3 = f2bf(xa.w - bf2f(h3));
            unsigned short l4 = f2bf(xb2.x - bf2f(h4)), l5 = f2bf(xb2.y - bf2f(h5));
            unsigned short l6 = f2bf(xb2.z - bf2f(h6)), l7 = f2bf(xb2.w - bf2f(h7));
            *(u16x4*)&a_hi[xrow][xsw]     = (u16x4){h0, h1, h2, h3};
            *(u16x4*)&a_hi[xrow][xsw + 4] = (u16x4){h4, h5, h6, h7};
            *(u16x4*)&a_lo[xrow][xsw]     = (u16x4){l0, l1, l2, l3};
            *(u16x4*)&a_lo[xrow][xsw + 4] = (u16x4){l4, l5, l6, l7};
        }
        #pragma unroll
        for (int j = 0; j < 4; j++) {
            const int cj = (wk >> 3) + j;
            const int sw = ((cj ^ (wrow & 7)) << 3);
            *(s16x8*)&bsh[wrow][sw] = wrh[j];
            *(s16x8*)&bsl[wrow][sw] = wrl[j];
        }
        __syncthreads();

        // refill relays (X: consumed at kc+4; W: consumed at kc+1 after
        // frag reads + 24 MFMAs + barrier -- covers L2 latency)
        if (tid < 256 && kc < 12) {
            xr[kc & 3][0] = *(const fx4*)(xb + (kc + 4) * 64);
            xr[kc & 3][1] = *(const fx4*)(xb + (kc + 4) * 64 + 4);
        }
        if (kc < 15) {
            #pragma unroll
            for (int j = 0; j < 4; j++) {
                wrh[j] = *(const s16x8*)(wt_hi + wb + (kc + 1) * 64 + j * 8);
                wrl[j] = *(const s16x8*)(wt_lo + wb + (kc + 1) * 64 + j * 8);
            }
        }

        // A frags (32 rows: sub=0,1), swizzled reads (proven conflict-free)
        s16x8 ah[2][2], al[2][2];
        #pragma unroll
        for (int sub = 0; sub < 2; sub++)
            #pragma unroll
            for (int ks = 0; ks < 2; ks++) {
                const int rr = sub * 16 + l15;
                const int sw = (((ks * 4 + quad) ^ (rr & 7)) << 3);
                ah[sub][ks] = *(const s16x8*)&a_hi[rr][sw];
                al[sub][ks] = *(const s16x8*)&a_lo[rr][sw];
            }
        #pragma unroll
        for (int nt = 0; nt < 2; nt++) {
            const int br = colg * 32 + nt * 16 + l15;
            #pragma unroll
            for (int ks = 0; ks < 2; ks++) {
                const int sw = (((ks * 4 + quad) ^ (br & 7)) << 3);
                s16x8 bh = *(const s16x8*)&bsh[br][sw];
                s16x8 bl = *(const s16x8*)&bsl[br][sw];
                #pragma unroll
                for (int sub = 0; sub < 2; sub++) {
                    acc[sub][nt] = __builtin_amdgcn_mfma_f32_16x16x32_bf16(ah[sub][ks], bh, acc[sub][nt], 0, 0, 0);
                    acc[sub][nt] = __builtin_amdgcn_mfma_f32_16x16x32_bf16(ah[sub][ks], bl, acc[sub][nt], 0, 0, 0);
                    acc[sub][nt] = __builtin_amdgcn_mfma_f32_16x16x32_bf16(al[sub][ks], bh, acc[sub][nt], 0, 0, 0);
                }
            }
        }
    }
    __syncthreads();   // all MFMA LDS reads done before vtr alias writes

    // epilogue: bias + relu; q -> hi/lo, k -> bf16, v -> transpose via LDS.
    // vtr: self-consistent [64 d][48] layout in bsh storage (3072 <= 12288).
    const float* bias = (y == 0) ? bq : (y == 1) ? bk : bv;
    const int b   = m0 >> 12;
    const int s0b = m0 & 4095;
    unsigned short* vtr = &bsh[0][0];  // alias: [64 d][48]

    #pragma unroll
    for (int sub = 0; sub < 2; sub++)
        #pragma unroll
        for (int nt = 0; nt < 2; nt++) {
            const int col = ch * 32 + nt * 16 + l15;
            const float bb = bias[col];
            const int rloc = sub * 16 + quad * 4;
            #pragma unroll
            for (int r = 0; r < 4; r++) {
                float v = fmaxf(acc[sub][nt][r] + bb, 0.f);
                size_t grow = (size_t)(m0 + rloc + r);
                if (y == 0) {
                    unsigned short h = f2bf(v);
                    unsigned short l = f2bf(v - bf2f(h));
                    q_hi[grow * 64 + col] = h;
                    q_lo[grow * 64 + col] = l;
                } else if (y == 1) {
                    k_bf[grow * 64 + col] = f2bf(v);
                } else {
                    vtr[col * 48 + rloc + r] = f2bf(v);  // transpose via LDS
                }
            }
        }
    __syncthreads();   // v-waves' vtr writes visible to storing threads
    if (tid < 256) {
        int row = tid >> 2;          // d 0..63
        int off = (tid & 3) * 8;     // s chunk (0..24)
        s16x8 vv = *(const s16x8*)&vtr[row * 48 + off];
        *(s16x8*)(vt_g + (size_t)(b * 64 + row) * 4096 + s0b + off) = vv;
    }
}

// ---------------------------------------------------------------------------
// Kernel 3 (v9): fused attention, KVBLK=128, 512-thread blocks owning 256
// q-rows (8 waves x 32q), grid 16x8x4 = 512 = 2 blocks/CU. T14 reg prefetch
// + setprio. LDS 56.3KB.  (unchanged -- measured 41.76us, FETCH clean)
// ---------------------------------------------------------------------------
__global__ __launch_bounds__(512, 2) void attn_kernel(
    const unsigned short* __restrict__ q_hi, const unsigned short* __restrict__ q_lo,
    const unsigned short* __restrict__ k_bf, const unsigned short* __restrict__ vt_g,
    unsigned short* __restrict__ pOb, float* __restrict__ pL)
{
    __shared__ __align__(16) unsigned short kt[128][72];     // [key][dim]
    __shared__ __align__(16) unsigned short vt[64][136];     // [dim][key]  (V^T)
    __shared__ __align__(16) unsigned short pt[8][32][40];   // per-wave P [q][key]

    const int tid  = threadIdx.x;
    const int lane = tid & 63;
    const int w    = tid >> 6;           // 0..7
    const int quad = lane >> 4;
    const int l15  = lane & 15;
    const int ck   = blockIdx.y;         // key chunk (512 keys = 4 tiles x 128)
    const int b    = blockIdx.z;
    const int q0   = blockIdx.x * 256;   // within batch

    // Q fragments for both 16-row subtiles (A layout: m=lane&15, k=quad*8+j)
    const size_t qbase = ((size_t)b * 4096 + q0 + w * 32 + l15) * 64 + quad * 8;
    s16x8 qh[2][2], ql[2][2];            // [sub][k-half]
    #pragma unroll
    for (int sub = 0; sub < 2; sub++) {
        qh[sub][0] = *(const s16x8*)(q_hi + qbase + sub * 1024);
        qh[sub][1] = *(const s16x8*)(q_hi + qbase + sub * 1024 + 32);
        ql[sub][0] = *(const s16x8*)(q_lo + qbase + sub * 1024);
        ql[sub][1] = *(const s16x8*)(q_lo + qbase + sub * 1024 + 32);
    }

    fx4 accO[2][4];
    #pragma unroll
    for (int sub = 0; sub < 2; sub++)
        #pragma unroll
        for (int nt = 0; nt < 4; nt++) accO[sub][nt] = (fx4){0.f, 0.f, 0.f, 0.f};
    float lsum[2][4] = {{0.f, 0.f, 0.f, 0.f}, {0.f, 0.f, 0.f, 0.f}};

    const unsigned short* kgb = k_bf + (size_t)b * 4096 * 64;  // [s][64]
    const unsigned short* vgb = vt_g + (size_t)b * 64 * 4096;  // [d][s]

    // staging: 512 threads; K: rows srow, srow+64 (full 128B rows);
    // V^T: dim srow, key chunks koff, koff+64 (256B contiguous per row/tile)
    const int srow = tid >> 3;            // 0..63
    const int koff = (tid & 7) * 8;       // 16B chunk offset

    const unsigned short* kp = kgb + (size_t)(ck * 512) * 64;   // tile stride 8192
    const unsigned short* vp = vgb + ck * 512;                  // tile stride 128

    // prologue prefetch of super-tile 0 into registers
    s16x8 nk0 = *(const s16x8*)(kp + (size_t)srow * 64 + koff);
    s16x8 nk1 = *(const s16x8*)(kp + (size_t)(srow + 64) * 64 + koff);
    s16x8 nv0 = *(const s16x8*)(vp + (size_t)srow * 4096 + koff);
    s16x8 nv1 = *(const s16x8*)(vp + (size_t)srow * 4096 + koff + 64);

    for (int t = 0; t < 4; t++) {
        // regs -> LDS (prev iter's trailing barrier guarantees readers done)
        *(s16x8*)&kt[srow][koff]      = nk0;
        *(s16x8*)&kt[srow + 64][koff] = nk1;
        *(s16x8*)&vt[srow][koff]      = nv0;
        *(s16x8*)&vt[srow][koff + 64] = nv1;
        __syncthreads();
        // issue next super-tile's loads; latency hides under compute below
        if (t < 3) {
            nk0 = *(const s16x8*)(kp + (size_t)(t + 1) * 8192 + (size_t)srow * 64 + koff);
            nk1 = *(const s16x8*)(kp + (size_t)(t + 1) * 8192 + (size_t)(srow + 64) * 64 + koff);
            nv0 = *(const s16x8*)(vp + (t + 1) * 128 + (size_t)srow * 4096 + koff);
            nv1 = *(const s16x8*)(vp + (t + 1) * 128 + (size_t)srow * 4096 + koff + 64);
        }

        #pragma unroll
        for (int h = 0; h < 2; h++) {
            #pragma unroll
            for (int kh = 0; kh < 2; kh++) {
                // S = Q K^T for this 32-key group; K frags feed both subtiles
                #pragma unroll
                for (int nt2 = 0; nt2 < 2; nt2++) {
                    const int key = h * 64 + kh * 32 + nt2 * 16 + l15;
                    s16x8 k0 = *(const s16x8*)&kt[key][quad * 8];
                    s16x8 k1 = *(const s16x8*)&kt[key][32 + quad * 8];
                    #pragma unroll
                    for (int sub = 0; sub < 2; sub++) {
                        fx4 sc = (fx4){0.f, 0.f, 0.f, 0.f};
                        __builtin_amdgcn_s_setprio(1);
                        sc = __builtin_amdgcn_mfma_f32_16x16x32_bf16(qh[sub][0], k0, sc, 0, 0, 0);
                        sc = __builtin_amdgcn_mfma_f32_16x16x32_bf16(ql[sub][0], k0, sc, 0, 0, 0);
                        sc = __builtin_amdgcn_mfma_f32_16x16x32_bf16(qh[sub][1], k1, sc, 0, 0, 0);
                        sc = __builtin_amdgcn_mfma_f32_16x16x32_bf16(ql[sub][1], k1, sc, 0, 0, 0);
                        __builtin_amdgcn_s_setprio(0);
                        // P = exp(S) -> bf16 -> wave-private LDS (C -> A layout)
                        #pragma unroll
                        for (int r = 0; r < 4; r++) {
                            float p = __builtin_amdgcn_exp2f(sc[r] * LOG2E);
                            unsigned short pb = f2bf(p);
                            lsum[sub][r] += bf2f(pb);   // denominator matches rounded numerator
                            pt[w][sub * 16 + quad * 4 + r][nt2 * 16 + l15] = pb;
                        }
                    }
                }
                // O += P V for this 32-key group; V frags feed both subtiles
                s16x8 pa0 = *(const s16x8*)&pt[w][l15][quad * 8];
                s16x8 pa1 = *(const s16x8*)&pt[w][16 + l15][quad * 8];
                __builtin_amdgcn_s_setprio(1);
                #pragma unroll
                for (int nt = 0; nt < 4; nt++) {
                    s16x8 vf = *(const s16x8*)&vt[nt * 16 + l15][h * 64 + kh * 32 + quad * 8];
                    accO[0][nt] = __builtin_amdgcn_mfma_f32_16x16x32_bf16(pa0, vf, accO[0][nt], 0, 0, 0);
                    accO[1][nt] = __builtin_amdgcn_mfma_f32_16x16x32_bf16(pa1, vf, accO[1][nt], 0, 0, 0);
                }
                __builtin_amdgcn_s_setprio(0);
            }
        }
        __syncthreads();   // this super-tile's readers drained before restage
    }

    // reduce row-sums across the 16 lanes sharing each row group
    #pragma unroll
    for (int sub = 0; sub < 2; sub++)
        #pragma unroll
        for (int r = 0; r < 4; r++) {
            float v = lsum[sub][r];
            #pragma unroll
            for (int o = 1; o < 16; o <<= 1) v += __shfl_xor(v, o);
            lsum[sub][r] = v;
        }
    // write partials: pOb[ck][b*4096+q][64] (bf16), pL[ck][b*4096+q] (fp32)
    #pragma unroll
    for (int sub = 0; sub < 2; sub++)
        #pragma unroll
        for (int r = 0; r < 4; r++) {
            int qrow = q0 + w * 32 + sub * 16 + quad * 4 + r;
            size_t grow = (size_t)b * 4096 + qrow;
            #pragma unroll
            for (int nt = 0; nt < 4; nt++)
                pOb[((size_t)ck * 16384 + grow) * 64 + nt * 16 + l15] = f2bf(accO[sub][nt][r]);
            if (l15 == 0)
                pL[(size_t)ck * 16384 + grow] = lsum[sub][r];
        }
}

// ---------------------------------------------------------------------------
// Kernel 4: combine partials: out = (sum_c pOb) * mask / (sum_c pL)  (unchanged)
// ---------------------------------------------------------------------------
__global__ __launch_bounds__(256) void combine_kernel(
    const unsigned short* __restrict__ pOb, const float* __restrict__ pL,
    const float* __restrict__ mask, float* __restrict__ out)
{
    int idx = blockIdx.x * 256 + threadIdx.x;   // 262144 = (b*4096+s)*16 + dgrp
    int q  = idx >> 4;
    int dg = idx & 15;
    fx4 s = (fx4){0.f, 0.f, 0.f, 0.f};
    float l = 0.f;
    #pragma unroll
    for (int c = 0; c < 8; c++) {
        u16x4 h = *(const u16x4*)(pOb + ((size_t)c * 16384 + q) * 64 + dg * 4);
        s.x += bf2f(h.x);
        s.y += bf2f(h.y);
        s.z += bf2f(h.z);
        s.w += bf2f(h.w);
        l += pL[(size_t)c * 16384 + q];
    }
    float scale = mask[q] / l;
    *(fx4*)(out + (size_t)q * 64 + dg * 4) = s * scale;
}

// ---------------------------------------------------------------------------
extern "C" void kernel_launch(void* const* d_in, const int* in_sizes, int n_in,
                              void* d_out, int out_size, void* d_ws, size_t ws_size,
                              hipStream_t stream)
{
    const float* X    = (const float*)d_in[0];
    const float* mask = (const float*)d_in[1];
    const float* Wq   = (const float*)d_in[2];
    const float* bq   = (const float*)d_in[3];
    const float* Wk   = (const float*)d_in[4];
    const float* bk   = (const float*)d_in[5];
    const float* Wv   = (const float*)d_in[6];
    const float* bv   = (const float*)d_in[7];
    float* out = (float*)d_out;

    char* ws = (char*)d_ws;
    unsigned short* q_hi  = (unsigned short*)(ws);                       // 2 MB
    unsigned short* q_lo  = (unsigned short*)(ws + (size_t)(2u << 20));  // 2 MB
    unsigned short* k_bf  = (unsigned short*)(ws + (size_t)(4u << 20));  // 2 MB
    unsigned short* vt_g  = (unsigned short*)(ws + (size_t)(6u << 20));  // 2 MB  [b][d][s]
    unsigned short* wt_hi = (unsigned short*)(ws + (size_t)(8u << 20));  // 384 KB
    unsigned short* wt_lo = (unsigned short*)(ws + (size_t)(8u << 20) + 393216);
    unsigned short* pOb   = (unsigned short*)(ws + (size_t)(9u << 20));  // 16 MB [8][16384][64] bf16
    float*          pL    = (float*)(ws + (size_t)(25u << 20));          // 512 KB [8][16384]

    hipLaunchKernelGGL(prep_w_kernel, dim3(3, 16), dim3(256), 0, stream,
                       Wq, Wk, Wv, wt_hi, wt_lo);
    hipLaunchKernelGGL(proj_kernel, dim3(512), dim3(384), 0, stream,
                       X, wt_hi, wt_lo, bq, bk, bv, q_hi, q_lo, k_bf, vt_g);
    hipLaunchKernelGGL(attn_kernel, dim3(16, 8, 4), dim3(512), 0, stream,
                       q_hi, q_lo, k_bf, vt_g, pOb, pL);
    hipLaunchKernelGGL(combine_kernel, dim3(1024), dim3(256), 0, stream,
                       pOb, pL, mask, out);
}

// Round 13
// 164.813 us; speedup vs baseline: 1.1059x; 1.1059x over previous
//
#include <hip/hip_runtime.h>

// B=4, S=4096, D_IN=1024, D_QK=D_V=64
// out = softmax(relu(XWq+bq) @ relu(XWk+bk)^T) @ relu(XWv+bv) * mask

typedef short s16x8 __attribute__((ext_vector_type(8)));   // 8 bf16 (4 VGPRs) MFMA frag
typedef float fx4   __attribute__((ext_vector_type(4)));   // MFMA accum frag
typedef unsigned short u16x4 __attribute__((ext_vector_type(4)));

#define LOG2E 1.4426950408889634f

__device__ __forceinline__ unsigned short f2bf(float x) {   // fp32 -> bf16 RTN
    unsigned int u = __float_as_uint(x);
    u += 0x7FFFu + ((u >> 16) & 1u);
    return (unsigned short)(u >> 16);
}
__device__ __forceinline__ float bf2f(unsigned short b) {
    return __uint_as_float(((unsigned int)b) << 16);
}

// ---------------------------------------------------------------------------
// Kernel 1: split W{q,k,v} [1024][64] fp32 into W^T hi/lo bf16 [3][64][1024].
// (unchanged)
// ---------------------------------------------------------------------------
__global__ __launch_bounds__(256) void prep_w_kernel(
    const float* __restrict__ Wq, const float* __restrict__ Wk, const float* __restrict__ Wv,
    unsigned short* __restrict__ wt_hi, unsigned short* __restrict__ wt_lo)
{
    __shared__ __align__(16) unsigned short sh[64][72];   // [c][k_local]
    __shared__ __align__(16) unsigned short sl[64][72];

    const int y  = blockIdx.x;
    const int kt = blockIdx.y;
    const float* W = (y == 0) ? Wq : (y == 1) ? Wk : Wv;
    const int t  = threadIdx.x;

    const int kl = t >> 2;
    const int c0 = (t & 3) * 16;
    const float* src = W + (size_t)(kt * 64 + kl) * 64 + c0;
    #pragma unroll
    for (int j = 0; j < 4; j++) {
        fx4 v = *(const fx4*)(src + j * 4);
        #pragma unroll
        for (int i = 0; i < 4; i++) {
            float x = v[i];
            unsigned short h = f2bf(x);
            unsigned short l = f2bf(x - bf2f(h));
            sh[c0 + j * 4 + i][kl] = h;
            sl[c0 + j * 4 + i][kl] = l;
        }
    }
    __syncthreads();

    const int c  = t >> 2;
    const int k0 = (t & 3) * 16;
    size_t o = (size_t)(y * 64 + c) * 1024 + kt * 64 + k0;
    *(s16x8*)(wt_hi + o)     = *(const s16x8*)&sh[c][k0];
    *(s16x8*)(wt_hi + o + 8) = *(const s16x8*)&sh[c][k0 + 8];
    *(s16x8*)(wt_lo + o)     = *(const s16x8*)&sl[c][k0];
    *(s16x8*)(wt_lo + o + 8) = *(const s16x8*)&sl[c][k0 + 8];
}

// ---------------------------------------------------------------------------
// Kernel 2 (v10b, REVERTED from v11): FUSED q/k/v projection, B in LDS,
// BK=128 phases, XOR-swizzled 128KiB LDS, 1 block/CU. Measured 41.7us,
// conflicts 41K. v11's 2-blocks/CU attempt (M=32, 384-thread blocks)
// REGRESSED to 66us with occupancy DROPPING to 15% -- the cross-block
// overlap never materialized; lever is measured-dead for this kernel.
// ---------------------------------------------------------------------------
__global__ __launch_bounds__(768, 3) void proj_kernel(
    const float* __restrict__ X,
    const unsigned short* __restrict__ wt_hi, const unsigned short* __restrict__ wt_lo,
    const float* __restrict__ bq, const float* __restrict__ bk, const float* __restrict__ bv,
    unsigned short* __restrict__ q_hi, unsigned short* __restrict__ q_lo,
    unsigned short* __restrict__ k_bf, unsigned short* __restrict__ vt_g)
{
    __shared__ __align__(16) unsigned short a_hi[2][64][64];   // [kc-slot][row][k] swz
    __shared__ __align__(16) unsigned short a_lo[2][64][64];
    __shared__ __align__(16) unsigned short bsh[2][192][64];   // [kc-slot][col][k] swz
    __shared__ __align__(16) unsigned short bsl[2][192][64];

    const int tid  = threadIdx.x;
    const int lane = tid & 63;
    const int w    = tid >> 6;      // 0..11
    const int quad = lane >> 4;
    const int l15  = lane & 15;
    const int rowg = w & 1;         // 32-row group
    const int colg = w >> 1;        // 0..5 = {q,k,v} x {col half}
    const int y    = colg >> 1;     // 0=q 1=k 2=v
    const int ch   = colg & 1;      // 32-col half within y

    const int m0 = blockIdx.x * 64;

    fx4 acc[2][2];                  // [sub 16 rows][nt 16 cols]
    #pragma unroll
    for (int i = 0; i < 2; i++)
        #pragma unroll
        for (int j = 0; j < 2; j++) acc[i][j] = (fx4){0.f, 0.f, 0.f, 0.f};

    // X staging: threads 0..511, 8 floats each (rows xrow, xrow+32)
    const int xrow = tid >> 4;        // 0..31 (tid<512)
    const int xoff = (tid & 15) * 4;  // logical col (0,4,...,60)
    const float* xb0 = X + (size_t)(m0 + xrow) * 1024 + xoff;
    const float* xb1 = X + (size_t)(m0 + xrow + 32) * 1024 + xoff;

    // W staging: all 768 threads, 32 B (hi) + 32 B (lo) each per kc
    const int wrow = tid >> 2;        // 0..191
    const int wk   = (tid & 3) * 16;  // logical k-offset (0,16,32,48)
    const size_t wb = (size_t)wrow * 1024 + wk;
    // swizzled physical chunk offsets (shorts) for the two 16B halves
    const int wsw0 = (((wk >> 3)     ^ (wrow & 7)) << 3);
    const int wsw1 = ((((wk >> 3) + 1) ^ (wrow & 7)) << 3);

    // register relays: X depth 4 kc, W depth 2 kc (v2/v6-proven pattern)
    fx4   xr[4][2];
    s16x8 wrh[2][2], wrl[2][2];
    if (tid < 512) {
        #pragma unroll
        for (int d = 0; d < 4; d++) {
            xr[d][0] = *(const fx4*)(xb0 + d * 64);
            xr[d][1] = *(const fx4*)(xb1 + d * 64);
        }
    }
    #pragma unroll
    for (int d = 0; d < 2; d++) {
        wrh[d][0] = *(const s16x8*)(wt_hi + wb + d * 64);
        wrh[d][1] = *(const s16x8*)(wt_hi + wb + d * 64 + 8);
        wrl[d][0] = *(const s16x8*)(wt_lo + wb + d * 64);
        wrl[d][1] = *(const s16x8*)(wt_lo + wb + d * 64 + 8);
    }

    #pragma unroll 2
    for (int ph = 0; ph < 8; ph++) {
        if (ph) __syncthreads();   // prev phase's LDS readers done
        // stage kc = 2ph (slot 0) and kc = 2ph+1 (slot 1)
        #pragma unroll
        for (int half = 0; half < 2; half++) {
            const int kc = 2 * ph + half;
            if (tid < 512) {
                #pragma unroll
                for (int i = 0; i < 2; i++) {
                    fx4 xv = xr[kc & 3][i];
                    unsigned short h0 = f2bf(xv.x), h1 = f2bf(xv.y), h2 = f2bf(xv.z), h3 = f2bf(xv.w);
                    unsigned short l0 = f2bf(xv.x - bf2f(h0)), l1 = f2bf(xv.y - bf2f(h1));
                    unsigned short l2 = f2bf(xv.z - bf2f(h2)), l3 = f2bf(xv.w - bf2f(h3));
                    const int row = xrow + i * 32;
                    const int sw  = ((((xoff >> 3) ^ (row & 7)) << 3) | (xoff & 7));
                    *(u16x4*)&a_hi[half][row][sw] = (u16x4){h0, h1, h2, h3};
                    *(u16x4*)&a_lo[half][row][sw] = (u16x4){l0, l1, l2, l3};
                }
            }
            *(s16x8*)&bsh[half][wrow][wsw0] = wrh[half][0];
            *(s16x8*)&bsh[half][wrow][wsw1] = wrh[half][1];
            *(s16x8*)&bsl[half][wrow][wsw0] = wrl[half][0];
            *(s16x8*)&bsl[half][wrow][wsw1] = wrl[half][1];
        }
        __syncthreads();

        // refill relays (consumed >= 1 full phase later: latency covered)
        if (tid < 512 && ph < 6) {
            #pragma unroll
            for (int half = 0; half < 2; half++) {
                const int kc = 2 * ph + 4 + half;      // slots (2ph)&3, (2ph+1)&3
                xr[kc & 3][0] = *(const fx4*)(xb0 + kc * 64);
                xr[kc & 3][1] = *(const fx4*)(xb1 + kc * 64);
            }
        }
        if (ph < 7) {
            #pragma unroll
            for (int half = 0; half < 2; half++) {
                const int kc = 2 * ph + 2 + half;      // slots 0, 1
                wrh[half][0] = *(const s16x8*)(wt_hi + wb + kc * 64);
                wrh[half][1] = *(const s16x8*)(wt_hi + wb + kc * 64 + 8);
                wrl[half][0] = *(const s16x8*)(wt_lo + wb + kc * 64);
                wrl[half][1] = *(const s16x8*)(wt_lo + wb + kc * 64 + 8);
            }
        }

        // compute both k-chunks sequentially (same kc order as v6 => bit-identical)
        #pragma unroll
        for (int half = 0; half < 2; half++) {
            s16x8 ah[2][2], al[2][2];
            #pragma unroll
            for (int sub = 0; sub < 2; sub++)
                #pragma unroll
                for (int ks = 0; ks < 2; ks++) {
                    const int rr = rowg * 32 + sub * 16 + l15;
                    const int sw = (((ks * 4 + quad) ^ (rr & 7)) << 3);
                    ah[sub][ks] = *(const s16x8*)&a_hi[half][rr][sw];
                    al[sub][ks] = *(const s16x8*)&a_lo[half][rr][sw];
                }
            #pragma unroll
            for (int nt = 0; nt < 2; nt++) {
                const int br = colg * 32 + nt * 16 + l15;
                #pragma unroll
                for (int ks = 0; ks < 2; ks++) {
                    const int sw = (((ks * 4 + quad) ^ (br & 7)) << 3);
                    s16x8 bh = *(const s16x8*)&bsh[half][br][sw];
                    s16x8 bl = *(const s16x8*)&bsl[half][br][sw];
                    #pragma unroll
                    for (int sub = 0; sub < 2; sub++) {
                        acc[sub][nt] = __builtin_amdgcn_mfma_f32_16x16x32_bf16(ah[sub][ks], bh, acc[sub][nt], 0, 0, 0);
                        acc[sub][nt] = __builtin_amdgcn_mfma_f32_16x16x32_bf16(ah[sub][ks], bl, acc[sub][nt], 0, 0, 0);
                        acc[sub][nt] = __builtin_amdgcn_mfma_f32_16x16x32_bf16(al[sub][ks], bh, acc[sub][nt], 0, 0, 0);
                    }
                }
            }
        }
    }
    __syncthreads();   // all MFMA LDS reads done before vtr alias writes

    // epilogue: bias + relu; q -> hi/lo, k -> bf16, v -> transpose via LDS.
    // vtr uses its own self-consistent [64][72] layout inside the a_hi
    // storage (8192 shorts >= 4608) -- independent of the main-loop swizzle.
    const float* bias = (y == 0) ? bq : (y == 1) ? bk : bv;
    const int b   = m0 >> 12;
    const int s0b = m0 & 4095;
    unsigned short* vtr = &a_hi[0][0][0];  // alias: [64 d][72]

    #pragma unroll
    for (int sub = 0; sub < 2; sub++)
        #pragma unroll
        for (int nt = 0; nt < 2; nt++) {
            const int col = ch * 32 + nt * 16 + l15;
            const float bb = bias[col];
            const int rloc = rowg * 32 + sub * 16 + quad * 4;
            #pragma unroll
            for (int r = 0; r < 4; r++) {
                float v = fmaxf(acc[sub][nt][r] + bb, 0.f);
                size_t grow = (size_t)(m0 + rloc + r);
                if (y == 0) {
                    unsigned short h = f2bf(v);
                    unsigned short l = f2bf(v - bf2f(h));
                    q_hi[grow * 64 + col] = h;
                    q_lo[grow * 64 + col] = l;
                } else if (y == 1) {
                    k_bf[grow * 64 + col] = f2bf(v);
                } else {
                    vtr[col * 72 + rloc + r] = f2bf(v);  // transpose via LDS
                }
            }
        }
    __syncthreads();   // v-waves' vtr writes visible to storing threads
    if (tid < 512) {
        int row = tid >> 3;          // d 0..63
        int off = (tid & 7) * 8;     // s chunk
        s16x8 vv = *(const s16x8*)&vtr[row * 72 + off];
        *(s16x8*)(vt_g + (size_t)(b * 64 + row) * 4096 + s0b + off) = vv;
    }
}

// ---------------------------------------------------------------------------
// Kernel 3 (v9): fused attention, KVBLK=128, 512-thread blocks owning 256
// q-rows (8 waves x 32q), grid 16x8x4 = 512 = 2 blocks/CU. T14 reg prefetch
// + setprio. LDS 56.3KB.  (unchanged -- measured 41.76us, FETCH clean)
// ---------------------------------------------------------------------------
__global__ __launch_bounds__(512, 2) void attn_kernel(
    const unsigned short* __restrict__ q_hi, const unsigned short* __restrict__ q_lo,
    const unsigned short* __restrict__ k_bf, const unsigned short* __restrict__ vt_g,
    unsigned short* __restrict__ pOb, float* __restrict__ pL)
{
    __shared__ __align__(16) unsigned short kt[128][72];     // [key][dim]
    __shared__ __align__(16) unsigned short vt[64][136];     // [dim][key]  (V^T)
    __shared__ __align__(16) unsigned short pt[8][32][40];   // per-wave P [q][key]

    const int tid  = threadIdx.x;
    const int lane = tid & 63;
    const int w    = tid >> 6;           // 0..7
    const int quad = lane >> 4;
    const int l15  = lane & 15;
    const int ck   = blockIdx.y;         // key chunk (512 keys = 4 tiles x 128)
    const int b    = blockIdx.z;
    const int q0   = blockIdx.x * 256;   // within batch

    // Q fragments for both 16-row subtiles (A layout: m=lane&15, k=quad*8+j)
    const size_t qbase = ((size_t)b * 4096 + q0 + w * 32 + l15) * 64 + quad * 8;
    s16x8 qh[2][2], ql[2][2];            // [sub][k-half]
    #pragma unroll
    for (int sub = 0; sub < 2; sub++) {
        qh[sub][0] = *(const s16x8*)(q_hi + qbase + sub * 1024);
        qh[sub][1] = *(const s16x8*)(q_hi + qbase + sub * 1024 + 32);
        ql[sub][0] = *(const s16x8*)(q_lo + qbase + sub * 1024);
        ql[sub][1] = *(const s16x8*)(q_lo + qbase + sub * 1024 + 32);
    }

    fx4 accO[2][4];
    #pragma unroll
    for (int sub = 0; sub < 2; sub++)
        #pragma unroll
        for (int nt = 0; nt < 4; nt++) accO[sub][nt] = (fx4){0.f, 0.f, 0.f, 0.f};
    float lsum[2][4] = {{0.f, 0.f, 0.f, 0.f}, {0.f, 0.f, 0.f, 0.f}};

    const unsigned short* kgb = k_bf + (size_t)b * 4096 * 64;  // [s][64]
    const unsigned short* vgb = vt_g + (size_t)b * 64 * 4096;  // [d][s]

    // staging: 512 threads; K: rows srow, srow+64 (full 128B rows);
    // V^T: dim srow, key chunks koff, koff+64 (256B contiguous per row/tile)
    const int srow = tid >> 3;            // 0..63
    const int koff = (tid & 7) * 8;       // 16B chunk offset

    const unsigned short* kp = kgb + (size_t)(ck * 512) * 64;   // tile stride 8192
    const unsigned short* vp = vgb + ck * 512;                  // tile stride 128

    // prologue prefetch of super-tile 0 into registers
    s16x8 nk0 = *(const s16x8*)(kp + (size_t)srow * 64 + koff);
    s16x8 nk1 = *(const s16x8*)(kp + (size_t)(srow + 64) * 64 + koff);
    s16x8 nv0 = *(const s16x8*)(vp + (size_t)srow * 4096 + koff);
    s16x8 nv1 = *(const s16x8*)(vp + (size_t)srow * 4096 + koff + 64);

    for (int t = 0; t < 4; t++) {
        // regs -> LDS (prev iter's trailing barrier guarantees readers done)
        *(s16x8*)&kt[srow][koff]      = nk0;
        *(s16x8*)&kt[srow + 64][koff] = nk1;
        *(s16x8*)&vt[srow][koff]      = nv0;
        *(s16x8*)&vt[srow][koff + 64] = nv1;
        __syncthreads();
        // issue next super-tile's loads; latency hides under compute below
        if (t < 3) {
            nk0 = *(const s16x8*)(kp + (size_t)(t + 1) * 8192 + (size_t)srow * 64 + koff);
            nk1 = *(const s16x8*)(kp + (size_t)(t + 1) * 8192 + (size_t)(srow + 64) * 64 + koff);
            nv0 = *(const s16x8*)(vp + (t + 1) * 128 + (size_t)srow * 4096 + koff);
            nv1 = *(const s16x8*)(vp + (t + 1) * 128 + (size_t)srow * 4096 + koff + 64);
        }

        #pragma unroll
        for (int h = 0; h < 2; h++) {
            #pragma unroll
            for (int kh = 0; kh < 2; kh++) {
                // S = Q K^T for this 32-key group; K frags feed both subtiles
                #pragma unroll
                for (int nt2 = 0; nt2 < 2; nt2++) {
                    const int key = h * 64 + kh * 32 + nt2 * 16 + l15;
                    s16x8 k0 = *(const s16x8*)&kt[key][quad * 8];
                    s16x8 k1 = *(const s16x8*)&kt[key][32 + quad * 8];
                    #pragma unroll
                    for (int sub = 0; sub < 2; sub++) {
                        fx4 sc = (fx4){0.f, 0.f, 0.f, 0.f};
                        __builtin_amdgcn_s_setprio(1);
                        sc = __builtin_amdgcn_mfma_f32_16x16x32_bf16(qh[sub][0], k0, sc, 0, 0, 0);
                        sc = __builtin_amdgcn_mfma_f32_16x16x32_bf16(ql[sub][0], k0, sc, 0, 0, 0);
                        sc = __builtin_amdgcn_mfma_f32_16x16x32_bf16(qh[sub][1], k1, sc, 0, 0, 0);
                        sc = __builtin_amdgcn_mfma_f32_16x16x32_bf16(ql[sub][1], k1, sc, 0, 0, 0);
                        __builtin_amdgcn_s_setprio(0);
                        // P = exp(S) -> bf16 -> wave-private LDS (C -> A layout)
                        #pragma unroll
                        for (int r = 0; r < 4; r++) {
                            float p = __builtin_amdgcn_exp2f(sc[r] * LOG2E);
                            unsigned short pb = f2bf(p);
                            lsum[sub][r] += bf2f(pb);   // denominator matches rounded numerator
                            pt[w][sub * 16 + quad * 4 + r][nt2 * 16 + l15] = pb;
                        }
                    }
                }
                // O += P V for this 32-key group; V frags feed both subtiles
                s16x8 pa0 = *(const s16x8*)&pt[w][l15][quad * 8];
                s16x8 pa1 = *(const s16x8*)&pt[w][16 + l15][quad * 8];
                __builtin_amdgcn_s_setprio(1);
                #pragma unroll
                for (int nt = 0; nt < 4; nt++) {
                    s16x8 vf = *(const s16x8*)&vt[nt * 16 + l15][h * 64 + kh * 32 + quad * 8];
                    accO[0][nt] = __builtin_amdgcn_mfma_f32_16x16x32_bf16(pa0, vf, accO[0][nt], 0, 0, 0);
                    accO[1][nt] = __builtin_amdgcn_mfma_f32_16x16x32_bf16(pa1, vf, accO[1][nt], 0, 0, 0);
                }
                __builtin_amdgcn_s_setprio(0);
            }
        }
        __syncthreads();   // this super-tile's readers drained before restage
    }

    // reduce row-sums across the 16 lanes sharing each row group
    #pragma unroll
    for (int sub = 0; sub < 2; sub++)
        #pragma unroll
        for (int r = 0; r < 4; r++) {
            float v = lsum[sub][r];
            #pragma unroll
            for (int o = 1; o < 16; o <<= 1) v += __shfl_xor(v, o);
            lsum[sub][r] = v;
        }
    // write partials: pOb[ck][b*4096+q][64] (bf16), pL[ck][b*4096+q] (fp32)
    #pragma unroll
    for (int sub = 0; sub < 2; sub++)
        #pragma unroll
        for (int r = 0; r < 4; r++) {
            int qrow = q0 + w * 32 + sub * 16 + quad * 4 + r;
            size_t grow = (size_t)b * 4096 + qrow;
            #pragma unroll
            for (int nt = 0; nt < 4; nt++)
                pOb[((size_t)ck * 16384 + grow) * 64 + nt * 16 + l15] = f2bf(accO[sub][nt][r]);
            if (l15 == 0)
                pL[(size_t)ck * 16384 + grow] = lsum[sub][r];
        }
}

// ---------------------------------------------------------------------------
// Kernel 4: combine partials: out = (sum_c pOb) * mask / (sum_c pL)  (unchanged)
// ---------------------------------------------------------------------------
__global__ __launch_bounds__(256) void combine_kernel(
    const unsigned short* __restrict__ pOb, const float* __restrict__ pL,
    const float* __restrict__ mask, float* __restrict__ out)
{
    int idx = blockIdx.x * 256 + threadIdx.x;   // 262144 = (b*4096+s)*16 + dgrp
    int q  = idx >> 4;
    int dg = idx & 15;
    fx4 s = (fx4){0.f, 0.f, 0.f, 0.f};
    float l = 0.f;
    #pragma unroll
    for (int c = 0; c < 8; c++) {
        u16x4 h = *(const u16x4*)(pOb + ((size_t)c * 16384 + q) * 64 + dg * 4);
        s.x += bf2f(h.x);
        s.y += bf2f(h.y);
        s.z += bf2f(h.z);
        s.w += bf2f(h.w);
        l += pL[(size_t)c * 16384 + q];
    }
    float scale = mask[q] / l;
    *(fx4*)(out + (size_t)q * 64 + dg * 4) = s * scale;
}

// ---------------------------------------------------------------------------
extern "C" void kernel_launch(void* const* d_in, const int* in_sizes, int n_in,
                              void* d_out, int out_size, void* d_ws, size_t ws_size,
                              hipStream_t stream)
{
    const float* X    = (const float*)d_in[0];
    const float* mask = (const float*)d_in[1];
    const float* Wq   = (const float*)d_in[2];
    const float* bq   = (const float*)d_in[3];
    const float* Wk   = (const float*)d_in[4];
    const float* bk   = (const float*)d_in[5];
    const float* Wv   = (const float*)d_in[6];
    const float* bv   = (const float*)d_in[7];
    float* out = (float*)d_out;

    char* ws = (char*)d_ws;
    unsigned short* q_hi  = (unsigned short*)(ws);                       // 2 MB
    unsigned short* q_lo  = (unsigned short*)(ws + (size_t)(2u << 20));  // 2 MB
    unsigned short* k_bf  = (unsigned short*)(ws + (size_t)(4u << 20));  // 2 MB
    unsigned short* vt_g  = (unsigned short*)(ws + (size_t)(6u << 20));  // 2 MB  [b][d][s]
    unsigned short* wt_hi = (unsigned short*)(ws + (size_t)(8u << 20));  // 384 KB
    unsigned short* wt_lo = (unsigned short*)(ws + (size_t)(8u << 20) + 393216);
    unsigned short* pOb   = (unsigned short*)(ws + (size_t)(9u << 20));  // 16 MB [8][16384][64] bf16
    float*          pL    = (float*)(ws + (size_t)(25u << 20));          // 512 KB [8][16384]

    hipLaunchKernelGGL(prep_w_kernel, dim3(3, 16), dim3(256), 0, stream,
                       Wq, Wk, Wv, wt_hi, wt_lo);
    hipLaunchKernelGGL(proj_kernel, dim3(256), dim3(768), 0, stream,
                       X, wt_hi, wt_lo, bq, bk, bv, q_hi, q_lo, k_bf, vt_g);
    hipLaunchKernelGGL(attn_kernel, dim3(16, 8, 4), dim3(512), 0, stream,
                       q_hi, q_lo, k_bf, vt_g, pOb, pL);
    hipLaunchKernelGGL(combine_kernel, dim3(1024), dim3(256), 0, stream,
                       pOb, pL, mask, out);
}